// Round 1
// baseline (2239.273 us; speedup 1.0000x reference)
//
#include <hip/hip_runtime.h>
#include <math.h>

// Problem constants
#define BB 16
#define C1 256     // in/out channels of the block
#define CHD 128    // hidden channels
#define HH 64
#define WW 64
#define NN 4096    // H*W
#define BN_EPS_C 1e-5f
// TEMPERATURE = sqrt(256) = 16 exactly
#define INV_T (1.0f/16.0f)

// ---------------------------------------------------------------------------
// Conv3x3(pad=1) + BN(running stats) + SiLU, fp32, LDS-tiled direct conv.
// grid: (Cout/64, H, B), block 256. Each block: one (b,h) row, 64 out-chans,
// all 64 w. Thread (tx=tid&15, ty=tid>>4) computes 4 co x 4 w.
// ---------------------------------------------------------------------------
__global__ __launch_bounds__(256) void conv_bn_silu_kernel(
    const float* __restrict__ x, const float* __restrict__ wgt,
    const float* __restrict__ gamma, const float* __restrict__ beta,
    const float* __restrict__ mean, const float* __restrict__ var,
    float* __restrict__ out, int Cin, int Cout)
{
    const int coBase = blockIdx.x * 64;
    const int h = blockIdx.y;
    const int b = blockIdx.z;
    const int tid = threadIdx.x;
    const int tx = tid & 15;   // w group (4 outputs)
    const int ty = tid >> 4;   // co group (4 outputs)

    __shared__ float xs[8][3][66];   // [ci_l][kh row][col+1], cols -1..64
    __shared__ float ws[64][73];     // [co_l][ci_l*9+k], padded stride 73

    float acc[4][4];
#pragma unroll
    for (int i = 0; i < 4; i++)
#pragma unroll
        for (int j = 0; j < 4; j++) acc[i][j] = 0.f;

    for (int ci0 = 0; ci0 < Cin; ci0 += 8) {
        // ---- stage input tile: 8 ci x 3 rows x 66 cols (zero padded) ----
        for (int idx = tid; idx < 8 * 3 * 66; idx += 256) {
            int c = idx / 198;
            int rem = idx - c * 198;
            int r = rem / 66;
            int cs = rem - r * 66;       // 0..65 -> col cs-1
            int col = cs - 1;
            int hr = h + r - 1;
            float v = 0.f;
            if (col >= 0 && col < 64 && hr >= 0 && hr < 64)
                v = x[(((size_t)b * Cin + ci0 + c) * 64 + hr) * 64 + col];
            xs[c][r][cs] = v;
        }
        // ---- stage weights: 64 co x (8 ci x 9) ----
        for (int idx = tid; idx < 64 * 72; idx += 256) {
            int co_l = idx / 72;
            int rem = idx - co_l * 72;   // ci_l*9 + k
            int ci_l = rem / 9;
            int k = rem - ci_l * 9;
            ws[co_l][rem] =
                wgt[(((size_t)(coBase + co_l) * Cin + ci0 + ci_l) * 9) + k];
        }
        __syncthreads();

        for (int ci_l = 0; ci_l < 8; ci_l++) {
#pragma unroll
            for (int kh = 0; kh < 3; kh++) {
                float xv[6];
#pragma unroll
                for (int t = 0; t < 6; t++) xv[t] = xs[ci_l][kh][tx * 4 + t];
#pragma unroll
                for (int kw = 0; kw < 3; kw++) {
                    float wv[4];
#pragma unroll
                    for (int i = 0; i < 4; i++)
                        wv[i] = ws[ty * 4 + i][ci_l * 9 + kh * 3 + kw];
#pragma unroll
                    for (int i = 0; i < 4; i++)
#pragma unroll
                        for (int j = 0; j < 4; j++)
                            acc[i][j] += wv[i] * xv[j + kw];
                }
            }
        }
        __syncthreads();
    }

    // ---- epilogue: BN + SiLU, coalesced store ----
#pragma unroll
    for (int i = 0; i < 4; i++) {
        int co = coBase + ty * 4 + i;
        float sc = gamma[co] * rsqrtf(var[co] + BN_EPS_C);
        float sh = beta[co] - mean[co] * sc;
#pragma unroll
        for (int j = 0; j < 4; j++) {
            float t = acc[i][j] * sc + sh;
            float s = t / (1.f + expf(-t));   // SiLU
            out[(((size_t)b * Cout + co) * 64 + h) * 64 + tx * 4 + j] = s;
        }
    }
}

// ---------------------------------------------------------------------------
// scores[b][c][d] = (y_b[c] . y_b[d]) / 16.   M=N=256, K=4096 per batch.
// grid: (4, 4, B), block 256, 64x64 tile, thread 4x4.
// ---------------------------------------------------------------------------
__global__ __launch_bounds__(256) void scores_kernel(
    const float* __restrict__ y, float* __restrict__ scores)
{
    const int b = blockIdx.z;
    const int cBase = blockIdx.y * 64;
    const int dBase = blockIdx.x * 64;
    const int tid = threadIdx.x;
    const int tx = tid & 15, ty = tid >> 4;

    __shared__ float As[64][33];
    __shared__ float Bs[64][33];

    float acc[4][4];
#pragma unroll
    for (int i = 0; i < 4; i++)
#pragma unroll
        for (int j = 0; j < 4; j++) acc[i][j] = 0.f;

    const float* yb = y + (size_t)b * C1 * NN;

    for (int k0 = 0; k0 < NN; k0 += 32) {
        for (int idx = tid; idx < 64 * 32; idx += 256) {
            int row = idx >> 5, k = idx & 31;
            As[row][k] = yb[(size_t)(cBase + row) * NN + k0 + k];
            Bs[row][k] = yb[(size_t)(dBase + row) * NN + k0 + k];
        }
        __syncthreads();
#pragma unroll
        for (int k = 0; k < 32; k++) {
            float av[4], bv[4];
#pragma unroll
            for (int i = 0; i < 4; i++) av[i] = As[ty * 4 + i][k];
#pragma unroll
            for (int j = 0; j < 4; j++) bv[j] = Bs[tx * 4 + j][k];
#pragma unroll
            for (int i = 0; i < 4; i++)
#pragma unroll
                for (int j = 0; j < 4; j++) acc[i][j] += av[i] * bv[j];
        }
        __syncthreads();
    }

#pragma unroll
    for (int i = 0; i < 4; i++)
#pragma unroll
        for (int j = 0; j < 4; j++)
            scores[((size_t)b * C1 + cBase + ty * 4 + i) * C1 + dBase + tx * 4 + j] =
                acc[i][j] * INV_T;
}

// ---------------------------------------------------------------------------
// Row softmax over 256 entries, in place. One wave per row. grid: B*C1.
// ---------------------------------------------------------------------------
__global__ __launch_bounds__(64) void softmax_kernel(float* __restrict__ scores)
{
    const int row = blockIdx.x;
    float* p = scores + (size_t)row * C1;
    const int lane = threadIdx.x;

    float4 v = ((const float4*)p)[lane];
    float m = fmaxf(fmaxf(v.x, v.y), fmaxf(v.z, v.w));
#pragma unroll
    for (int off = 32; off >= 1; off >>= 1)
        m = fmaxf(m, __shfl_xor(m, off, 64));

    float4 e;
    e.x = expf(v.x - m); e.y = expf(v.y - m);
    e.z = expf(v.z - m); e.w = expf(v.w - m);
    float s = e.x + e.y + e.z + e.w;
#pragma unroll
    for (int off = 32; off >= 1; off >>= 1)
        s += __shfl_xor(s, off, 64);
    float inv = 1.f / s;
    e.x *= inv; e.y *= inv; e.z *= inv; e.w *= inv;
    ((float4*)p)[lane] = e;
}

// ---------------------------------------------------------------------------
// out[b][c][n] = x[b][c][n] + sum_d attn[b][c][d] * y[b][d][n]
// M=256 (c), N=4096 (n), K=256 (d). grid: (64, 4, B), block 256, 64x64 tile.
// ---------------------------------------------------------------------------
__global__ __launch_bounds__(256) void out_kernel(
    const float* __restrict__ attn, const float* __restrict__ y,
    const float* __restrict__ x, float* __restrict__ out)
{
    const int b = blockIdx.z;
    const int cBase = blockIdx.y * 64;
    const int nBase = blockIdx.x * 64;
    const int tid = threadIdx.x;
    const int tx = tid & 15, ty = tid >> 4;

    __shared__ float As[64][33];  // attn[c][d chunk]
    __shared__ float Bs[32][65];  // y[d][n]

    float acc[4][4];
#pragma unroll
    for (int i = 0; i < 4; i++)
#pragma unroll
        for (int j = 0; j < 4; j++) acc[i][j] = 0.f;

    for (int d0 = 0; d0 < C1; d0 += 32) {
        for (int idx = tid; idx < 64 * 32; idx += 256) {
            int row = idx >> 5, k = idx & 31;
            As[row][k] = attn[((size_t)b * C1 + cBase + row) * C1 + d0 + k];
        }
        for (int idx = tid; idx < 32 * 64; idx += 256) {
            int row = idx >> 6, col = idx & 63;
            Bs[row][col] = y[((size_t)b * C1 + d0 + row) * NN + nBase + col];
        }
        __syncthreads();
#pragma unroll
        for (int k = 0; k < 32; k++) {
            float av[4], bv[4];
#pragma unroll
            for (int i = 0; i < 4; i++) av[i] = As[ty * 4 + i][k];
#pragma unroll
            for (int j = 0; j < 4; j++) bv[j] = Bs[k][tx * 4 + j];
#pragma unroll
            for (int i = 0; i < 4; i++)
#pragma unroll
                for (int j = 0; j < 4; j++) acc[i][j] += av[i] * bv[j];
        }
        __syncthreads();
    }

#pragma unroll
    for (int i = 0; i < 4; i++) {
#pragma unroll
        for (int j = 0; j < 4; j++) {
            size_t o = ((size_t)b * C1 + cBase + ty * 4 + i) * NN + nBase + tx * 4 + j;
            out[o] = x[o] + acc[i][j];
        }
    }
}

// ---------------------------------------------------------------------------
extern "C" void kernel_launch(void* const* d_in, const int* in_sizes, int n_in,
                              void* d_out, int out_size, void* d_ws, size_t ws_size,
                              hipStream_t stream)
{
    const float* x  = (const float*)d_in[0];
    const float* w1 = (const float*)d_in[1];
    const float* g1 = (const float*)d_in[2];
    const float* b1 = (const float*)d_in[3];
    const float* m1 = (const float*)d_in[4];
    const float* v1 = (const float*)d_in[5];
    const float* w2 = (const float*)d_in[6];
    const float* g2 = (const float*)d_in[7];
    const float* b2 = (const float*)d_in[8];
    const float* m2 = (const float*)d_in[9];
    const float* v2 = (const float*)d_in[10];
    float* out = (float*)d_out;

    // workspace layout
    float* y1 = (float*)d_ws;                       // [16,128,64,64] 33.6 MB
    float* y  = y1 + (size_t)BB * CHD * NN;         // [16,256,64,64] 67.1 MB
    float* sc = y  + (size_t)BB * C1 * NN;          // [16,256,256]    4.2 MB

    // conv1: 256 -> 128
    conv_bn_silu_kernel<<<dim3(CHD / 64, HH, BB), 256, 0, stream>>>(
        x, w1, g1, b1, m1, v1, y1, C1, CHD);
    // conv2: 128 -> 256
    conv_bn_silu_kernel<<<dim3(C1 / 64, HH, BB), 256, 0, stream>>>(
        y1, w2, g2, b2, m2, v2, y, CHD, C1);
    // scores = (y/16) @ y^T per batch
    scores_kernel<<<dim3(4, 4, BB), 256, 0, stream>>>(y, sc);
    // softmax rows
    softmax_kernel<<<dim3(BB * C1), 64, 0, stream>>>(sc);
    // out = x + attn @ y
    out_kernel<<<dim3(NN / 64, 4, BB), 256, 0, stream>>>(sc, y, x, out);
}

// Round 3
// 785.887 us; speedup vs baseline: 2.8494x; 2.8494x over previous
//
#include <hip/hip_runtime.h>
#include <math.h>

// Problem constants
#define BB 16
#define C1 256     // in/out channels of the block
#define CHD 128    // hidden channels
#define NN 4096    // H*W
#define INV_T (1.0f/16.0f)   // TEMPERATURE = sqrt(256) = 16

typedef _Float16 half8 __attribute__((ext_vector_type(8)));
typedef __attribute__((ext_vector_type(4))) float f32x4;

__device__ inline unsigned short f2h(float f) {
    _Float16 h = (_Float16)f;            // RN conversion
    return __builtin_bit_cast(unsigned short, h);
}

// async global->LDS, 16B per lane; LDS dest = wave-uniform base + lane*16
#define GLDS(g, l) __builtin_amdgcn_global_load_lds(                              \
    (const __attribute__((address_space(1))) unsigned int*)(g),                   \
    (__attribute__((address_space(3))) unsigned int*)(l), 16, 0, 0)

// ---------------------------------------------------------------------------
// NCHW fp32 -> padded NHWC fp16:  xh[b][hp][w][c], hp in [0,66), rows 0 & 65 zero.
// grid: (C/64, 66, B), block 256
// ---------------------------------------------------------------------------
__global__ __launch_bounds__(256) void nchw_to_nhwc_f16(
    const float* __restrict__ x, unsigned short* __restrict__ xh, int C)
{
    const int c0 = blockIdx.x * 64;
    const int hp = blockIdx.y;
    const int b  = blockIdx.z;

    if (hp == 0 || hp == 65) {
        for (int idx = threadIdx.x; idx < 1024; idx += 256) {
            int w = idx >> 4, cq = (idx & 15) * 4;
            ushort4 z; z.x = z.y = z.z = z.w = 0;
            *(ushort4*)&xh[(((size_t)b * 66 + hp) * 64 + w) * C + c0 + cq] = z;
        }
        return;
    }
    const int h = hp - 1;
    __shared__ float ts[64][65];
    for (int idx = threadIdx.x; idx < 4096; idx += 256) {
        int cl = idx >> 6, w = idx & 63;
        ts[cl][w] = x[(((size_t)b * C + c0 + cl) * 64 + h) * 64 + w];
    }
    __syncthreads();
    for (int idx = threadIdx.x; idx < 1024; idx += 256) {
        int w = idx >> 4, cq = (idx & 15) * 4;
        ushort4 o;
        o.x = f2h(ts[cq + 0][w]); o.y = f2h(ts[cq + 1][w]);
        o.z = f2h(ts[cq + 2][w]); o.w = f2h(ts[cq + 3][w]);
        *(ushort4*)&xh[(((size_t)b * 66 + hp) * 64 + w) * C + c0 + cq] = o;
    }
}

// ---------------------------------------------------------------------------
// Pack conv weights [Cout][Cin][3][3] fp32 -> [kk][Cout][Cin] fp16
// ---------------------------------------------------------------------------
__global__ __launch_bounds__(256) void pack_w_kernel(
    const float* __restrict__ w, unsigned short* __restrict__ wT, int Cout, int Cin)
{
    int idx = blockIdx.x * 256 + threadIdx.x;
    int total = Cout * Cin * 9;
    if (idx >= total) return;
    int ci = idx % Cin; int t = idx / Cin; int co = t % Cout; int kk = t / Cout;
    wT[idx] = f2h(w[((size_t)co * Cin + ci) * 9 + kk]);
}

// ---------------------------------------------------------------------------
// Zero the pad rows (0 and 65) of y1h [B][66][64][128] fp16
// ---------------------------------------------------------------------------
__global__ __launch_bounds__(256) void zero_y1h_pads(unsigned short* __restrict__ y1h)
{
    int idx = blockIdx.x * 256 + threadIdx.x;   // 65536 ushort4 stores
    int b = idx >> 12;
    int row = ((idx >> 11) & 1) ? 65 : 0;
    int inner = idx & 2047;
    ushort4 z; z.x = z.y = z.z = z.w = 0;
    *(ushort4*)&y1h[(((size_t)b * 66 + row) * 64) * 128 + inner * 4] = z;
}

// ---------------------------------------------------------------------------
// Implicit-GEMM conv3x3 + BN + SiLU via fp16 MFMA (fp32 accumulate).
// Input xh: padded NHWC fp16 [B][66][64][Cin]. Weights wT: [9][Cout][Cin] fp16.
// Block: 256 thr = 4 waves. Block tile: 64 co x 4 rows x 64 cols. Wave w -> row h0+w.
// grid: (Cout/64, 16, B)
// ---------------------------------------------------------------------------
__global__ __launch_bounds__(256) void conv_mfma_kernel(
    const unsigned short* __restrict__ xh, const unsigned short* __restrict__ wT,
    const float* __restrict__ gamma, const float* __restrict__ beta,
    const float* __restrict__ mean, const float* __restrict__ var,
    unsigned short* __restrict__ outNHWC,   // non-null for conv1 (fp16)
    float* __restrict__ outNCHW,            // non-null for conv2 (fp32)
    int Cin, int Cout)
{
    const int tid  = threadIdx.x;
    const int wid  = tid >> 6;      // wave id = output row within tile
    const int lane = tid & 63;
    const int ln   = lane & 15;
    const int q    = lane >> 4;
    const int coBase = blockIdx.x * 64;
    const int h0     = blockIdx.y * 4;
    const int b      = blockIdx.z;

    __shared__ unsigned short xs[6 * 66 * 32];   // [row][col 0..65][ci32], 25344 B
    __shared__ unsigned short ws[9 * 64 * 32];   // [kk][co64][ci32],       36864 B
    __shared__ float bnsc[64], bnsh[64];

    if (tid < 64) {
        int co = coBase + tid;
        float sc = gamma[co] * rsqrtf(var[co] + 1e-5f);
        bnsc[tid] = sc;
        bnsh[tid] = beta[co] - mean[co] * sc;
    }
    // zero halo columns 0 and 65 (all ci chunks see zeros there)
    if (tid < 48) {
        int r = tid >> 3, cpart = tid & 7;
        int col = (cpart < 4) ? 0 : 65;
        ushort4 z; z.x = z.y = z.z = z.w = 0;
        *(ushort4*)&xs[r * 2112 + col * 32 + (cpart & 3) * 8] = z;
        *(ushort4*)&xs[r * 2112 + col * 32 + (cpart & 3) * 8 + 4] = z;
    }
    __syncthreads();

    f32x4 acc[4][4] = {};

    const int nChunk = Cin >> 5;
    for (int ck = 0; ck < nChunk; ck++) {
        const int ci0 = ck << 5;
        // ---- stage: 36 KB weights + 24 KB input slab, 60 x 1KB wave issues ----
        for (int it = wid; it < 60; it += 4) {
            if (it < 36) {
                int el   = it * 512 + lane * 8;      // element offset into ws
                int kkco = el >> 5;
                int kk   = kkco >> 6;
                int co   = kkco & 63;
                int cip  = el & 31;
                const unsigned short* g =
                    wT + (((size_t)kk * Cout + coBase + co) * Cin + ci0 + cip);
                GLDS(g, ws + it * 512);
            } else {
                int j = it - 36;                     // 0..23
                int r = j >> 2, p = j & 3;
                int w   = p * 16 + (lane >> 2);
                int cip = (lane & 3) * 8;
                const unsigned short* g =
                    xh + ((((size_t)b * 66 + h0 + r) * 64 + w) * Cin + ci0 + cip);
                GLDS(g, xs + r * 2112 + (1 + p * 16) * 32);
            }
        }
        __syncthreads();

        // ---- compute: 9 taps x 16 MFMA ----
#pragma unroll
        for (int kk = 0; kk < 9; kk++) {
            const int kh = kk / 3, kw = kk % 3;
            half8 af[4], bfr[4];
#pragma unroll
            for (int mi = 0; mi < 4; mi++)
                af[mi] = *(const half8*)&ws[(kk * 64 + mi * 16 + ln) * 32 + q * 8];
#pragma unroll
            for (int ni = 0; ni < 4; ni++)
                bfr[ni] = *(const half8*)&xs[(wid + kh) * 2112 + (ni * 16 + ln + kw) * 32 + q * 8];
#pragma unroll
            for (int mi = 0; mi < 4; mi++)
#pragma unroll
                for (int ni = 0; ni < 4; ni++)
                    acc[mi][ni] = __builtin_amdgcn_mfma_f32_16x16x32_f16(
                        af[mi], bfr[ni], acc[mi][ni], 0, 0, 0);
        }
        __syncthreads();
    }

    // ---- epilogue: BN + SiLU ----
    const int orow = h0 + wid;
    if (outNHWC) {
#pragma unroll
        for (int mi = 0; mi < 4; mi++) {
            int col0 = mi * 16 + q * 4;
            float s0 = bnsc[col0 + 0], h0s = bnsh[col0 + 0];
            float s1 = bnsc[col0 + 1], h1s = bnsh[col0 + 1];
            float s2 = bnsc[col0 + 2], h2s = bnsh[col0 + 2];
            float s3 = bnsc[col0 + 3], h3s = bnsh[col0 + 3];
#pragma unroll
            for (int ni = 0; ni < 4; ni++) {
                int w = ni * 16 + ln;
                f32x4 a = acc[mi][ni];
                float t0 = a.x * s0 + h0s, t1 = a.y * s1 + h1s;
                float t2 = a.z * s2 + h2s, t3 = a.w * s3 + h3s;
                ushort4 o;
                o.x = f2h(t0 / (1.f + __expf(-t0)));
                o.y = f2h(t1 / (1.f + __expf(-t1)));
                o.z = f2h(t2 / (1.f + __expf(-t2)));
                o.w = f2h(t3 / (1.f + __expf(-t3)));
                *(ushort4*)&outNHWC[(((size_t)b * 66 + orow + 1) * 64 + w) * Cout
                                    + coBase + col0] = o;
            }
        }
    } else {
#pragma unroll
        for (int mi = 0; mi < 4; mi++) {
            int col0 = mi * 16 + q * 4;
#pragma unroll
            for (int ni = 0; ni < 4; ni++) {
                int w = ni * 16 + ln;
                f32x4 a = acc[mi][ni];
                float vals[4] = {a.x, a.y, a.z, a.w};
#pragma unroll
                for (int r = 0; r < 4; r++) {
                    int co = coBase + col0 + r;
                    float t = vals[r] * bnsc[col0 + r] + bnsh[col0 + r];
                    outNCHW[(((size_t)b * Cout + co) * 64 + orow) * 64 + w] =
                        t / (1.f + __expf(-t));
                }
            }
        }
    }
}

// ---------------------------------------------------------------------------
// scores[b][c][d] = (y_b[c] . y_b[d]) / 16.   M=N=256, K=4096 per batch. fp32.
// ---------------------------------------------------------------------------
__global__ __launch_bounds__(256) void scores_kernel(
    const float* __restrict__ y, float* __restrict__ scores)
{
    const int b = blockIdx.z;
    const int cBase = blockIdx.y * 64;
    const int dBase = blockIdx.x * 64;
    const int tid = threadIdx.x;
    const int tx = tid & 15, ty = tid >> 4;

    __shared__ float As[64][33];
    __shared__ float Bs[64][33];

    float acc[4][4];
#pragma unroll
    for (int i = 0; i < 4; i++)
#pragma unroll
        for (int j = 0; j < 4; j++) acc[i][j] = 0.f;

    const float* yb = y + (size_t)b * C1 * NN;

    for (int k0 = 0; k0 < NN; k0 += 32) {
        for (int idx = tid; idx < 64 * 32; idx += 256) {
            int row = idx >> 5, k = idx & 31;
            As[row][k] = yb[(size_t)(cBase + row) * NN + k0 + k];
            Bs[row][k] = yb[(size_t)(dBase + row) * NN + k0 + k];
        }
        __syncthreads();
#pragma unroll
        for (int k = 0; k < 32; k++) {
            float av[4], bv[4];
#pragma unroll
            for (int i = 0; i < 4; i++) av[i] = As[ty * 4 + i][k];
#pragma unroll
            for (int j = 0; j < 4; j++) bv[j] = Bs[tx * 4 + j][k];
#pragma unroll
            for (int i = 0; i < 4; i++)
#pragma unroll
                for (int j = 0; j < 4; j++) acc[i][j] += av[i] * bv[j];
        }
        __syncthreads();
    }

#pragma unroll
    for (int i = 0; i < 4; i++)
#pragma unroll
        for (int j = 0; j < 4; j++)
            scores[((size_t)b * C1 + cBase + ty * 4 + i) * C1 + dBase + tx * 4 + j] =
                acc[i][j] * INV_T;
}

// ---------------------------------------------------------------------------
// Row softmax over 256 entries, in place. One wave per row.
// ---------------------------------------------------------------------------
__global__ __launch_bounds__(64) void softmax_kernel(float* __restrict__ scores)
{
    const int row = blockIdx.x;
    float* p = scores + (size_t)row * C1;
    const int lane = threadIdx.x;

    float4 v = ((const float4*)p)[lane];
    float m = fmaxf(fmaxf(v.x, v.y), fmaxf(v.z, v.w));
#pragma unroll
    for (int off = 32; off >= 1; off >>= 1)
        m = fmaxf(m, __shfl_xor(m, off, 64));

    float4 e;
    e.x = expf(v.x - m); e.y = expf(v.y - m);
    e.z = expf(v.z - m); e.w = expf(v.w - m);
    float s = e.x + e.y + e.z + e.w;
#pragma unroll
    for (int off = 32; off >= 1; off >>= 1)
        s += __shfl_xor(s, off, 64);
    float inv = 1.f / s;
    e.x *= inv; e.y *= inv; e.z *= inv; e.w *= inv;
    ((float4*)p)[lane] = e;
}

// ---------------------------------------------------------------------------
// out[b][c][n] = x[b][c][n] + sum_d attn[b][c][d] * y[b][d][n]
// ---------------------------------------------------------------------------
__global__ __launch_bounds__(256) void out_kernel(
    const float* __restrict__ attn, const float* __restrict__ y,
    const float* __restrict__ x, float* __restrict__ out)
{
    const int b = blockIdx.z;
    const int cBase = blockIdx.y * 64;
    const int nBase = blockIdx.x * 64;
    const int tid = threadIdx.x;
    const int tx = tid & 15, ty = tid >> 4;

    __shared__ float As[64][33];
    __shared__ float Bs[32][65];

    float acc[4][4];
#pragma unroll
    for (int i = 0; i < 4; i++)
#pragma unroll
        for (int j = 0; j < 4; j++) acc[i][j] = 0.f;

    for (int d0 = 0; d0 < C1; d0 += 32) {
        for (int idx = tid; idx < 64 * 32; idx += 256) {
            int row = idx >> 5, k = idx & 31;
            As[row][k] = attn[((size_t)b * C1 + cBase + row) * C1 + d0 + k];
        }
        for (int idx = tid; idx < 32 * 64; idx += 256) {
            int row = idx >> 6, col = idx & 63;
            Bs[row][col] = y[((size_t)b * C1 + d0 + row) * NN + nBase + col];
        }
        __syncthreads();
#pragma unroll
        for (int k = 0; k < 32; k++) {
            float av[4], bv[4];
#pragma unroll
            for (int i = 0; i < 4; i++) av[i] = As[ty * 4 + i][k];
#pragma unroll
            for (int j = 0; j < 4; j++) bv[j] = Bs[k][tx * 4 + j];
#pragma unroll
            for (int i = 0; i < 4; i++)
#pragma unroll
                for (int j = 0; j < 4; j++) acc[i][j] += av[i] * bv[j];
        }
        __syncthreads();
    }

#pragma unroll
    for (int i = 0; i < 4; i++) {
#pragma unroll
        for (int j = 0; j < 4; j++) {
            size_t o = ((size_t)b * C1 + cBase + ty * 4 + i) * NN + nBase + tx * 4 + j;
            out[o] = x[o] + acc[i][j];
        }
    }
}

// ---------------------------------------------------------------------------
extern "C" void kernel_launch(void* const* d_in, const int* in_sizes, int n_in,
                              void* d_out, int out_size, void* d_ws, size_t ws_size,
                              hipStream_t stream)
{
    const float* x  = (const float*)d_in[0];
    const float* w1 = (const float*)d_in[1];
    const float* g1 = (const float*)d_in[2];
    const float* b1 = (const float*)d_in[3];
    const float* m1 = (const float*)d_in[4];
    const float* v1 = (const float*)d_in[5];
    const float* w2 = (const float*)d_in[6];
    const float* g2 = (const float*)d_in[7];
    const float* b2 = (const float*)d_in[8];
    const float* m2 = (const float*)d_in[9];
    const float* v2 = (const float*)d_in[10];
    float* out = (float*)d_out;

    // workspace layout: xh 34.6M | y1h 17.3M | wt1 0.59M | wt2 0.59M | y 67.1M | sc 4.2M
    unsigned short* xh  = (unsigned short*)d_ws;            // [16][66][64][256] fp16
    unsigned short* y1h = xh  + (size_t)BB * 66 * 64 * C1;  // [16][66][64][128] fp16
    unsigned short* wt1 = y1h + (size_t)BB * 66 * 64 * CHD; // [9][128][256] fp16
    unsigned short* wt2 = wt1 + (size_t)9 * CHD * C1;       // [9][256][128] fp16
    float* y  = (float*)(wt2 + (size_t)9 * C1 * CHD);       // [16][256][64][64] fp32
    float* sc = y + (size_t)BB * C1 * NN;                   // [16][256][256] fp32

    // pre-pass
    nchw_to_nhwc_f16<<<dim3(C1 / 64, 66, BB), 256, 0, stream>>>(x, xh, C1);
    pack_w_kernel<<<(9 * CHD * C1 + 255) / 256, 256, 0, stream>>>(w1, wt1, CHD, C1);
    pack_w_kernel<<<(9 * C1 * CHD + 255) / 256, 256, 0, stream>>>(w2, wt2, C1, CHD);
    zero_y1h_pads<<<256, 256, 0, stream>>>(y1h);

    // conv1: 256 -> 128, fp16 NHWC out (padded rows)
    conv_mfma_kernel<<<dim3(CHD / 64, 16, BB), 256, 0, stream>>>(
        xh, wt1, g1, b1, m1, v1, y1h, nullptr, C1, CHD);
    // conv2: 128 -> 256, fp32 NCHW out
    conv_mfma_kernel<<<dim3(C1 / 64, 16, BB), 256, 0, stream>>>(
        y1h, wt2, g2, b2, m2, v2, nullptr, y, CHD, C1);

    // attention (fp32, unchanged)
    scores_kernel<<<dim3(4, 4, BB), 256, 0, stream>>>(y, sc);
    softmax_kernel<<<dim3(BB * C1), 64, 0, stream>>>(sc);
    out_kernel<<<dim3(NN / 64, 4, BB), 256, 0, stream>>>(sc, y, x, out);
}

// Round 4
// 353.618 us; speedup vs baseline: 6.3325x; 2.2224x over previous
//
#include <hip/hip_runtime.h>
#include <math.h>

// Problem constants
#define BB 16
#define C1 256     // in/out channels of the block
#define CHD 128    // hidden channels
#define NN 4096    // H*W
#define INV_T (1.0f/16.0f)   // TEMPERATURE = sqrt(256) = 16

typedef _Float16 half8 __attribute__((ext_vector_type(8)));
typedef __attribute__((ext_vector_type(4))) float f32x4;

__device__ inline unsigned short f2h(float f) {
    _Float16 h = (_Float16)f;            // RN conversion
    return __builtin_bit_cast(unsigned short, h);
}

// async global->LDS, 16B per lane; LDS dest = wave-uniform base + lane*16
#define GLDS(g, l) __builtin_amdgcn_global_load_lds(                              \
    (const __attribute__((address_space(1))) unsigned int*)(g),                   \
    (__attribute__((address_space(3))) unsigned int*)(l), 16, 0, 0)

// ---------------------------------------------------------------------------
// NCHW fp32 -> padded NHWC fp16:  xh[b][hp][w][c], hp in [0,66), rows 0 & 65 zero.
// ---------------------------------------------------------------------------
__global__ __launch_bounds__(256) void nchw_to_nhwc_f16(
    const float* __restrict__ x, unsigned short* __restrict__ xh, int C)
{
    const int c0 = blockIdx.x * 64;
    const int hp = blockIdx.y;
    const int b  = blockIdx.z;

    if (hp == 0 || hp == 65) {
        for (int idx = threadIdx.x; idx < 1024; idx += 256) {
            int w = idx >> 4, cq = (idx & 15) * 4;
            ushort4 z; z.x = z.y = z.z = z.w = 0;
            *(ushort4*)&xh[(((size_t)b * 66 + hp) * 64 + w) * C + c0 + cq] = z;
        }
        return;
    }
    const int h = hp - 1;
    __shared__ float ts[64][65];
    for (int idx = threadIdx.x; idx < 4096; idx += 256) {
        int cl = idx >> 6, w = idx & 63;
        ts[cl][w] = x[(((size_t)b * C + c0 + cl) * 64 + h) * 64 + w];
    }
    __syncthreads();
    for (int idx = threadIdx.x; idx < 1024; idx += 256) {
        int w = idx >> 4, cq = (idx & 15) * 4;
        ushort4 o;
        o.x = f2h(ts[cq + 0][w]); o.y = f2h(ts[cq + 1][w]);
        o.z = f2h(ts[cq + 2][w]); o.w = f2h(ts[cq + 3][w]);
        *(ushort4*)&xh[(((size_t)b * 66 + hp) * 64 + w) * C + c0 + cq] = o;
    }
}

// ---------------------------------------------------------------------------
// Pack conv weights [Cout][Cin][3][3] fp32 -> [kk][Cout][Cin] fp16
// ---------------------------------------------------------------------------
__global__ __launch_bounds__(256) void pack_w_kernel(
    const float* __restrict__ w, unsigned short* __restrict__ wT, int Cout, int Cin)
{
    int idx = blockIdx.x * 256 + threadIdx.x;
    int total = Cout * Cin * 9;
    if (idx >= total) return;
    int ci = idx % Cin; int t = idx / Cin; int co = t % Cout; int kk = t / Cout;
    wT[idx] = f2h(w[((size_t)co * Cin + ci) * 9 + kk]);
}

// ---------------------------------------------------------------------------
// Zero the pad rows (0 and 65) of y1h [B][66][64][128] fp16
// ---------------------------------------------------------------------------
__global__ __launch_bounds__(256) void zero_y1h_pads(unsigned short* __restrict__ y1h)
{
    int idx = blockIdx.x * 256 + threadIdx.x;   // 65536 ushort4 stores
    int b = idx >> 12;
    int row = ((idx >> 11) & 1) ? 65 : 0;
    int inner = idx & 2047;
    ushort4 z; z.x = z.y = z.z = z.w = 0;
    *(ushort4*)&y1h[(((size_t)b * 66 + row) * 64) * 128 + inner * 4] = z;
}

// ---------------------------------------------------------------------------
// Implicit-GEMM conv3x3 + BN + SiLU via fp16 MFMA (fp32 accumulate).
// conv1 path: outNHWC != nullptr -> fp16 padded NHWC.
// conv2 path: writes y_hi/y_lo (NCHW fp16 split) + y_hiT (NHWC fp16).
// grid: (Cout/64, 16, B), block 256 = 4 waves, wave w -> output row h0+w.
// ---------------------------------------------------------------------------
__global__ __launch_bounds__(256) void conv_mfma_kernel(
    const unsigned short* __restrict__ xh, const unsigned short* __restrict__ wT,
    const float* __restrict__ gamma, const float* __restrict__ beta,
    const float* __restrict__ mean, const float* __restrict__ var,
    unsigned short* __restrict__ outNHWC,
    unsigned short* __restrict__ yhi, unsigned short* __restrict__ ylo,
    unsigned short* __restrict__ yhiT,
    int Cin, int Cout)
{
    const int tid  = threadIdx.x;
    const int wid  = tid >> 6;
    const int lane = tid & 63;
    const int ln   = lane & 15;
    const int q    = lane >> 4;
    const int coBase = blockIdx.x * 64;
    const int h0     = blockIdx.y * 4;
    const int b      = blockIdx.z;

    __shared__ unsigned short xs[6 * 66 * 32];   // [row][col 0..65][ci32]
    __shared__ unsigned short ws[9 * 64 * 32];   // [kk][co64][ci32]
    __shared__ float bnsc[64], bnsh[64];

    if (tid < 64) {
        int co = coBase + tid;
        float sc = gamma[co] * rsqrtf(var[co] + 1e-5f);
        bnsc[tid] = sc;
        bnsh[tid] = beta[co] - mean[co] * sc;
    }
    if (tid < 48) {   // zero halo columns 0 and 65
        int r = tid >> 3, cpart = tid & 7;
        int col = (cpart < 4) ? 0 : 65;
        ushort4 z; z.x = z.y = z.z = z.w = 0;
        *(ushort4*)&xs[r * 2112 + col * 32 + (cpart & 3) * 8] = z;
        *(ushort4*)&xs[r * 2112 + col * 32 + (cpart & 3) * 8 + 4] = z;
    }
    __syncthreads();

    f32x4 acc[4][4] = {};

    const int nChunk = Cin >> 5;
    for (int ck = 0; ck < nChunk; ck++) {
        const int ci0 = ck << 5;
        for (int it = wid; it < 60; it += 4) {
            if (it < 36) {
                int el   = it * 512 + lane * 8;
                int kkco = el >> 5;
                int kk   = kkco >> 6;
                int co   = kkco & 63;
                int cip  = el & 31;
                const unsigned short* g =
                    wT + (((size_t)kk * Cout + coBase + co) * Cin + ci0 + cip);
                GLDS(g, ws + it * 512);
            } else {
                int j = it - 36;
                int r = j >> 2, p = j & 3;
                int w   = p * 16 + (lane >> 2);
                int cip = (lane & 3) * 8;
                const unsigned short* g =
                    xh + ((((size_t)b * 66 + h0 + r) * 64 + w) * Cin + ci0 + cip);
                GLDS(g, xs + r * 2112 + (1 + p * 16) * 32);
            }
        }
        __syncthreads();

#pragma unroll
        for (int kk = 0; kk < 9; kk++) {
            const int kh = kk / 3, kw = kk % 3;
            half8 af[4], bfr[4];
#pragma unroll
            for (int mi = 0; mi < 4; mi++)
                af[mi] = *(const half8*)&ws[(kk * 64 + mi * 16 + ln) * 32 + q * 8];
#pragma unroll
            for (int ni = 0; ni < 4; ni++)
                bfr[ni] = *(const half8*)&xs[(wid + kh) * 2112 + (ni * 16 + ln + kw) * 32 + q * 8];
#pragma unroll
            for (int mi = 0; mi < 4; mi++)
#pragma unroll
                for (int ni = 0; ni < 4; ni++)
                    acc[mi][ni] = __builtin_amdgcn_mfma_f32_16x16x32_f16(
                        af[mi], bfr[ni], acc[mi][ni], 0, 0, 0);
        }
        __syncthreads();
    }

    const int orow = h0 + wid;
    if (outNHWC) {
#pragma unroll
        for (int mi = 0; mi < 4; mi++) {
            int col0 = mi * 16 + q * 4;
            float s0 = bnsc[col0 + 0], h0s = bnsh[col0 + 0];
            float s1 = bnsc[col0 + 1], h1s = bnsh[col0 + 1];
            float s2 = bnsc[col0 + 2], h2s = bnsh[col0 + 2];
            float s3 = bnsc[col0 + 3], h3s = bnsh[col0 + 3];
#pragma unroll
            for (int ni = 0; ni < 4; ni++) {
                int w = ni * 16 + ln;
                f32x4 a = acc[mi][ni];
                float t0 = a.x * s0 + h0s, t1 = a.y * s1 + h1s;
                float t2 = a.z * s2 + h2s, t3 = a.w * s3 + h3s;
                ushort4 o;
                o.x = f2h(t0 / (1.f + __expf(-t0)));
                o.y = f2h(t1 / (1.f + __expf(-t1)));
                o.z = f2h(t2 / (1.f + __expf(-t2)));
                o.w = f2h(t3 / (1.f + __expf(-t3)));
                *(ushort4*)&outNHWC[(((size_t)b * 66 + orow + 1) * 64 + w) * Cout
                                    + coBase + col0] = o;
            }
        }
    } else {
        // conv2: y_hi / y_lo NCHW fp16 split + y_hiT NHWC fp16
#pragma unroll
        for (int mi = 0; mi < 4; mi++) {
            int col0 = mi * 16 + q * 4;
#pragma unroll
            for (int ni = 0; ni < 4; ni++) {
                int w = ni * 16 + ln;
                f32x4 a = acc[mi][ni];
                float vals[4] = {a.x, a.y, a.z, a.w};
                ushort4 hv;
                unsigned short* hvp = (unsigned short*)&hv;
#pragma unroll
                for (int r = 0; r < 4; r++) {
                    int co = coBase + col0 + r;
                    float t = vals[r] * bnsc[col0 + r] + bnsh[col0 + r];
                    float s = t / (1.f + __expf(-t));
                    _Float16 hh = (_Float16)s;
                    hvp[r] = __builtin_bit_cast(unsigned short, hh);
                    float lo = s - (float)hh;
                    size_t o = (((size_t)b * Cout + co) * 64 + orow) * 64 + w;
                    yhi[o] = hvp[r];
                    ylo[o] = f2h(lo);
                }
                *(ushort4*)&yhiT[((size_t)b * 4096 + orow * 64 + w) * Cout
                                 + coBase + col0] = hv;
            }
        }
    }
}

// ---------------------------------------------------------------------------
// scores = (y . y^T)/16 with fp16-split compensation: hi*hi + hi*lo + lo*hi.
// y_hi/y_lo: [b][c=256][n=4096] fp16. Block: 64x64 tile, 4 waves of 32x32.
// K-chunks of 64, XOR-swizzled LDS (conflict-free ds_read_b128).
// grid: (4, 4, 16)
// ---------------------------------------------------------------------------
__global__ __launch_bounds__(256) void scores_mfma_kernel(
    const unsigned short* __restrict__ yhi, const unsigned short* __restrict__ ylo,
    float* __restrict__ scores)
{
    const int b  = blockIdx.z;
    const int cB = blockIdx.y * 64;
    const int dB = blockIdx.x * 64;
    const int tid  = threadIdx.x;
    const int wid  = tid >> 6;
    const int lane = tid & 63;
    const int ln   = lane & 15;
    const int q    = lane >> 4;
    const int wm   = wid >> 1, wn = wid & 1;

    __shared__ unsigned short lds[4 * 64 * 64];  // Ah | Al | Bh | Bl, 32 KB

    // wave `wid` stages tile `wid`
    const unsigned short* src = (wid & 1) ? ylo : yhi;
    const int rb = (wid < 2) ? cB : dB;
    unsigned short* ldst = lds + wid * 4096;
    const int r8 = lane >> 3;
    const int gq = (lane & 7) ^ r8;          // XOR swizzle: global k-group

    f32x4 acc[2][2] = {};

    for (int ck = 0; ck < 64; ck++) {
        const int n0 = ck * 64;
#pragma unroll
        for (int i = 0; i < 8; i++) {
            const unsigned short* g =
                src + ((size_t)b * 256 + rb + i * 8 + r8) * 4096 + n0 + gq * 8;
            GLDS(g, ldst + i * 512);
        }
        __syncthreads();

#pragma unroll
        for (int kwin = 0; kwin < 2; kwin++) {
            const int cc = (((kwin * 4 + q) ^ (ln & 7))) * 8;
            half8 ah[2], al[2], bh[2], bl[2];
#pragma unroll
            for (int mi = 0; mi < 2; mi++) {
                int row = wm * 32 + mi * 16 + ln;
                ah[mi] = *(const half8*)&lds[0 * 4096 + row * 64 + cc];
                al[mi] = *(const half8*)&lds[1 * 4096 + row * 64 + cc];
            }
#pragma unroll
            for (int ni = 0; ni < 2; ni++) {
                int row = wn * 32 + ni * 16 + ln;
                bh[ni] = *(const half8*)&lds[2 * 4096 + row * 64 + cc];
                bl[ni] = *(const half8*)&lds[3 * 4096 + row * 64 + cc];
            }
#pragma unroll
            for (int mi = 0; mi < 2; mi++)
#pragma unroll
                for (int ni = 0; ni < 2; ni++) {
                    acc[mi][ni] = __builtin_amdgcn_mfma_f32_16x16x32_f16(
                        ah[mi], bh[ni], acc[mi][ni], 0, 0, 0);
                    acc[mi][ni] = __builtin_amdgcn_mfma_f32_16x16x32_f16(
                        ah[mi], bl[ni], acc[mi][ni], 0, 0, 0);
                    acc[mi][ni] = __builtin_amdgcn_mfma_f32_16x16x32_f16(
                        al[mi], bh[ni], acc[mi][ni], 0, 0, 0);
                }
        }
        __syncthreads();
    }

#pragma unroll
    for (int mi = 0; mi < 2; mi++)
#pragma unroll
        for (int ni = 0; ni < 2; ni++) {
            f32x4 a = acc[mi][ni];
            float vals[4] = {a.x, a.y, a.z, a.w};
#pragma unroll
            for (int r = 0; r < 4; r++) {
                int c = cB + wm * 32 + mi * 16 + q * 4 + r;
                int d = dB + wn * 32 + ni * 16 + ln;
                scores[((size_t)b * C1 + c) * C1 + d] = vals[r] * INV_T;
            }
        }
}

// ---------------------------------------------------------------------------
// Row softmax over 256 entries; reads fp32 scores, writes fp16 attn.
// ---------------------------------------------------------------------------
__global__ __launch_bounds__(64) void softmax_kernel(
    const float* __restrict__ scores, unsigned short* __restrict__ attn16)
{
    const int row = blockIdx.x;
    const float* p = scores + (size_t)row * C1;
    const int lane = threadIdx.x;

    float4 v = ((const float4*)p)[lane];
    float m = fmaxf(fmaxf(v.x, v.y), fmaxf(v.z, v.w));
#pragma unroll
    for (int off = 32; off >= 1; off >>= 1)
        m = fmaxf(m, __shfl_xor(m, off, 64));

    float4 e;
    e.x = expf(v.x - m); e.y = expf(v.y - m);
    e.z = expf(v.z - m); e.w = expf(v.w - m);
    float s = e.x + e.y + e.z + e.w;
#pragma unroll
    for (int off = 32; off >= 1; off >>= 1)
        s += __shfl_xor(s, off, 64);
    float inv = 1.f / s;
    ushort4 o;
    o.x = f2h(e.x * inv); o.y = f2h(e.y * inv);
    o.z = f2h(e.z * inv); o.w = f2h(e.w * inv);
    *(ushort4*)&attn16[(size_t)row * C1 + lane * 4] = o;
}

// ---------------------------------------------------------------------------
// out[b][c][n] = x[b][c][n] + sum_d attn[c][d] * y[d][n]  via fp16 MFMA.
// A = attn16 [b][c][d], B = yhiT [b][n][d] (both k=d contiguous).
// Block tile 64c x 128n, 4 waves of 32x64. K-chunks of 64 (4 chunks).
// grid: (32, 4, 16)
// ---------------------------------------------------------------------------
__global__ __launch_bounds__(256) void out_mfma_kernel(
    const unsigned short* __restrict__ attn16, const unsigned short* __restrict__ yhiT,
    const float* __restrict__ x, float* __restrict__ out)
{
    const int b  = blockIdx.z;
    const int cB = blockIdx.y * 64;
    const int nB = blockIdx.x * 128;
    const int tid  = threadIdx.x;
    const int wid  = tid >> 6;
    const int lane = tid & 63;
    const int ln   = lane & 15;
    const int q    = lane >> 4;
    const int wm   = wid >> 1, wn = wid & 1;

    __shared__ unsigned short As[64 * 64];    //  8 KB
    __shared__ unsigned short Bs[128 * 64];   // 16 KB

    const int r8 = lane >> 3;
    const int gq = (lane & 7) ^ r8;

    f32x4 acc[2][4] = {};

    for (int ck = 0; ck < 4; ck++) {
        const int d0 = ck * 64;
        for (int it = wid; it < 24; it += 4) {
            if (it < 8) {
                const unsigned short* g =
                    attn16 + ((size_t)b * 256 + cB + it * 8 + r8) * 256 + d0 + gq * 8;
                GLDS(g, As + it * 512);
            } else {
                int j = it - 8;
                const unsigned short* g =
                    yhiT + ((size_t)b * 4096 + nB + j * 8 + r8) * 256 + d0 + gq * 8;
                GLDS(g, Bs + j * 512);
            }
        }
        __syncthreads();

#pragma unroll
        for (int kwin = 0; kwin < 2; kwin++) {
            const int cc = (((kwin * 4 + q) ^ (ln & 7))) * 8;
            half8 af[2], bfr[4];
#pragma unroll
            for (int mi = 0; mi < 2; mi++)
                af[mi] = *(const half8*)&As[(wm * 32 + mi * 16 + ln) * 64 + cc];
#pragma unroll
            for (int ni = 0; ni < 4; ni++)
                bfr[ni] = *(const half8*)&Bs[(wn * 64 + ni * 16 + ln) * 64 + cc];
#pragma unroll
            for (int mi = 0; mi < 2; mi++)
#pragma unroll
                for (int ni = 0; ni < 4; ni++)
                    acc[mi][ni] = __builtin_amdgcn_mfma_f32_16x16x32_f16(
                        af[mi], bfr[ni], acc[mi][ni], 0, 0, 0);
        }
        __syncthreads();
    }

#pragma unroll
    for (int mi = 0; mi < 2; mi++)
#pragma unroll
        for (int ni = 0; ni < 4; ni++) {
            f32x4 a = acc[mi][ni];
            float vals[4] = {a.x, a.y, a.z, a.w};
#pragma unroll
            for (int r = 0; r < 4; r++) {
                int c = cB + wm * 32 + mi * 16 + q * 4 + r;
                int n = nB + wn * 64 + ni * 16 + ln;
                size_t o = ((size_t)b * C1 + c) * NN + n;
                out[o] = x[o] + vals[r];
            }
        }
}

// ---------------------------------------------------------------------------
extern "C" void kernel_launch(void* const* d_in, const int* in_sizes, int n_in,
                              void* d_out, int out_size, void* d_ws, size_t ws_size,
                              hipStream_t stream)
{
    const float* x  = (const float*)d_in[0];
    const float* w1 = (const float*)d_in[1];
    const float* g1 = (const float*)d_in[2];
    const float* b1 = (const float*)d_in[3];
    const float* m1 = (const float*)d_in[4];
    const float* v1 = (const float*)d_in[5];
    const float* w2 = (const float*)d_in[6];
    const float* g2 = (const float*)d_in[7];
    const float* b2 = (const float*)d_in[8];
    const float* m2 = (const float*)d_in[9];
    const float* v2 = (const float*)d_in[10];
    float* out = (float*)d_out;

    // workspace (120.2 MB total, all within known-safe 124.6 MB):
    //  xh [17,301,504 us] -- dead after conv1, REUSED as y_hi [16,777,216 us]
    //  y1h [8,650,752 us] -- dead after conv2, REUSED as sc (fp32) + attn16
    //  wt1, wt2, y_lo, y_hiT
    unsigned short* xh   = (unsigned short*)d_ws;
    unsigned short* y1h  = xh  + (size_t)17301504;
    unsigned short* wt1  = y1h + (size_t)8650752;
    unsigned short* wt2  = wt1 + (size_t)294912;
    unsigned short* ylo  = wt2 + (size_t)294912;
    unsigned short* yhiT = ylo + (size_t)16777216;
    unsigned short* yhi  = xh;                         // alias (xh dead)
    float*          sc   = (float*)y1h;                // alias (y1h dead)
    unsigned short* attn16 = (unsigned short*)(sc + 1048576);

    // pre-pass
    nchw_to_nhwc_f16<<<dim3(C1 / 64, 66, BB), 256, 0, stream>>>(x, xh, C1);
    pack_w_kernel<<<(9 * CHD * C1 + 255) / 256, 256, 0, stream>>>(w1, wt1, CHD, C1);
    pack_w_kernel<<<(9 * C1 * CHD + 255) / 256, 256, 0, stream>>>(w2, wt2, C1, CHD);
    zero_y1h_pads<<<256, 256, 0, stream>>>(y1h);

    // conv1: 256 -> 128, fp16 NHWC out (padded rows)
    conv_mfma_kernel<<<dim3(CHD / 64, 16, BB), 256, 0, stream>>>(
        xh, wt1, g1, b1, m1, v1, y1h, nullptr, nullptr, nullptr, C1, CHD);
    // conv2: 128 -> 256, fp16 split outputs (overwrites xh region with yhi)
    conv_mfma_kernel<<<dim3(C1 / 64, 16, BB), 256, 0, stream>>>(
        y1h, wt2, g2, b2, m2, v2, nullptr, yhi, ylo, yhiT, CHD, C1);

    // attention: compensated fp16 MFMA scores -> softmax -> fp16 MFMA PV + residual
    scores_mfma_kernel<<<dim3(4, 4, BB), 256, 0, stream>>>(yhi, ylo, sc);
    softmax_kernel<<<dim3(BB * C1), 64, 0, stream>>>(sc, attn16);
    out_mfma_kernel<<<dim3(NN / 128, 4, BB), 256, 0, stream>>>(attn16, yhiT, x, out);
}

// Round 5
// 332.527 us; speedup vs baseline: 6.7341x; 1.0634x over previous
//
#include <hip/hip_runtime.h>
#include <math.h>

// Problem constants
#define BB 16
#define C1 256     // in/out channels of the block
#define CHD 128    // hidden channels
#define NN 4096    // H*W
#define INV_T (1.0f/16.0f)   // TEMPERATURE = sqrt(256) = 16

typedef _Float16 half8 __attribute__((ext_vector_type(8)));
typedef __attribute__((ext_vector_type(4))) float f32x4;

__device__ inline unsigned short f2h(float f) {
    _Float16 h = (_Float16)f;            // RN conversion
    return __builtin_bit_cast(unsigned short, h);
}

// async global->LDS, 16B per lane; LDS dest = wave-uniform base + lane*16
#define GLDS(g, l) __builtin_amdgcn_global_load_lds(                              \
    (const __attribute__((address_space(1))) unsigned int*)(g),                   \
    (__attribute__((address_space(3))) unsigned int*)(l), 16, 0, 0)

// ---------------------------------------------------------------------------
// NCHW fp32 -> padded NHWC fp16:  xh[b][hp][w][c], hp in [0,66), rows 0 & 65 zero.
// ---------------------------------------------------------------------------
__global__ __launch_bounds__(256) void nchw_to_nhwc_f16(
    const float* __restrict__ x, unsigned short* __restrict__ xh, int C)
{
    const int c0 = blockIdx.x * 64;
    const int hp = blockIdx.y;
    const int b  = blockIdx.z;

    if (hp == 0 || hp == 65) {
        for (int idx = threadIdx.x; idx < 1024; idx += 256) {
            int w = idx >> 4, cq = (idx & 15) * 4;
            ushort4 z; z.x = z.y = z.z = z.w = 0;
            *(ushort4*)&xh[(((size_t)b * 66 + hp) * 64 + w) * C + c0 + cq] = z;
        }
        return;
    }
    const int h = hp - 1;
    __shared__ float ts[64][65];
    for (int idx = threadIdx.x; idx < 4096; idx += 256) {
        int cl = idx >> 6, w = idx & 63;
        ts[cl][w] = x[(((size_t)b * C + c0 + cl) * 64 + h) * 64 + w];
    }
    __syncthreads();
    for (int idx = threadIdx.x; idx < 1024; idx += 256) {
        int w = idx >> 4, cq = (idx & 15) * 4;
        ushort4 o;
        o.x = f2h(ts[cq + 0][w]); o.y = f2h(ts[cq + 1][w]);
        o.z = f2h(ts[cq + 2][w]); o.w = f2h(ts[cq + 3][w]);
        *(ushort4*)&xh[(((size_t)b * 66 + hp) * 64 + w) * C + c0 + cq] = o;
    }
}

// ---------------------------------------------------------------------------
// Pack conv weights [Cout][Cin][3][3] fp32 -> [kk][Cout][Cin] fp16
// ---------------------------------------------------------------------------
__global__ __launch_bounds__(256) void pack_w_kernel(
    const float* __restrict__ w, unsigned short* __restrict__ wT, int Cout, int Cin)
{
    int idx = blockIdx.x * 256 + threadIdx.x;
    int total = Cout * Cin * 9;
    if (idx >= total) return;
    int ci = idx % Cin; int t = idx / Cin; int co = t % Cout; int kk = t / Cout;
    wT[idx] = f2h(w[((size_t)co * Cin + ci) * 9 + kk]);
}

// ---------------------------------------------------------------------------
// Zero the pad rows (0 and 65) of y1h [B][66][64][128] fp16
// ---------------------------------------------------------------------------
__global__ __launch_bounds__(256) void zero_y1h_pads(unsigned short* __restrict__ y1h)
{
    int idx = blockIdx.x * 256 + threadIdx.x;   // 65536 ushort4 stores
    int b = idx >> 12;
    int row = ((idx >> 11) & 1) ? 65 : 0;
    int inner = idx & 2047;
    ushort4 z; z.x = z.y = z.z = z.w = 0;
    *(ushort4*)&y1h[(((size_t)b * 66 + row) * 64) * 128 + inner * 4] = z;
}

// ---------------------------------------------------------------------------
// Implicit-GEMM conv3x3 + BN + SiLU via fp16 MFMA (fp32 accumulate).
// conv1 path: outNHWC != nullptr -> fp16 padded NHWC.
// conv2 path: writes y_hi (NCHW fp16) + y_hiT (NHWC fp16).
// grid: (Cout/64, 16, B), block 256 = 4 waves, wave w -> output row h0+w.
// ---------------------------------------------------------------------------
__global__ __launch_bounds__(256) void conv_mfma_kernel(
    const unsigned short* __restrict__ xh, const unsigned short* __restrict__ wT,
    const float* __restrict__ gamma, const float* __restrict__ beta,
    const float* __restrict__ mean, const float* __restrict__ var,
    unsigned short* __restrict__ outNHWC,
    unsigned short* __restrict__ yhi, unsigned short* __restrict__ yhiT,
    int Cin, int Cout)
{
    const int tid  = threadIdx.x;
    const int wid  = tid >> 6;
    const int lane = tid & 63;
    const int ln   = lane & 15;
    const int q    = lane >> 4;
    const int coBase = blockIdx.x * 64;
    const int h0     = blockIdx.y * 4;
    const int b      = blockIdx.z;

    __shared__ unsigned short xs[6 * 66 * 32];   // [row][col 0..65][ci32]
    __shared__ unsigned short ws[9 * 64 * 32];   // [kk][co64][ci32]
    __shared__ float bnsc[64], bnsh[64];

    if (tid < 64) {
        int co = coBase + tid;
        float sc = gamma[co] * rsqrtf(var[co] + 1e-5f);
        bnsc[tid] = sc;
        bnsh[tid] = beta[co] - mean[co] * sc;
    }
    if (tid < 48) {   // zero halo columns 0 and 65
        int r = tid >> 3, cpart = tid & 7;
        int col = (cpart < 4) ? 0 : 65;
        ushort4 z; z.x = z.y = z.z = z.w = 0;
        *(ushort4*)&xs[r * 2112 + col * 32 + (cpart & 3) * 8] = z;
        *(ushort4*)&xs[r * 2112 + col * 32 + (cpart & 3) * 8 + 4] = z;
    }
    __syncthreads();

    f32x4 acc[4][4] = {};

    const int nChunk = Cin >> 5;
    for (int ck = 0; ck < nChunk; ck++) {
        const int ci0 = ck << 5;
        for (int it = wid; it < 60; it += 4) {
            if (it < 36) {
                int el   = it * 512 + lane * 8;
                int kkco = el >> 5;
                int kk   = kkco >> 6;
                int co   = kkco & 63;
                int cip  = el & 31;
                const unsigned short* g =
                    wT + (((size_t)kk * Cout + coBase + co) * Cin + ci0 + cip);
                GLDS(g, ws + it * 512);
            } else {
                int j = it - 36;
                int r = j >> 2, p = j & 3;
                int w   = p * 16 + (lane >> 2);
                int cip = (lane & 3) * 8;
                const unsigned short* g =
                    xh + ((((size_t)b * 66 + h0 + r) * 64 + w) * Cin + ci0 + cip);
                GLDS(g, xs + r * 2112 + (1 + p * 16) * 32);
            }
        }
        __syncthreads();

#pragma unroll
        for (int kk = 0; kk < 9; kk++) {
            const int kh = kk / 3, kw = kk % 3;
            half8 af[4], bfr[4];
#pragma unroll
            for (int mi = 0; mi < 4; mi++)
                af[mi] = *(const half8*)&ws[(kk * 64 + mi * 16 + ln) * 32 + q * 8];
#pragma unroll
            for (int ni = 0; ni < 4; ni++)
                bfr[ni] = *(const half8*)&xs[(wid + kh) * 2112 + (ni * 16 + ln + kw) * 32 + q * 8];
#pragma unroll
            for (int mi = 0; mi < 4; mi++)
#pragma unroll
                for (int ni = 0; ni < 4; ni++)
                    acc[mi][ni] = __builtin_amdgcn_mfma_f32_16x16x32_f16(
                        af[mi], bfr[ni], acc[mi][ni], 0, 0, 0);
        }
        __syncthreads();
    }

    const int orow = h0 + wid;
    if (outNHWC) {
#pragma unroll
        for (int mi = 0; mi < 4; mi++) {
            int col0 = mi * 16 + q * 4;
            float s0 = bnsc[col0 + 0], h0s = bnsh[col0 + 0];
            float s1 = bnsc[col0 + 1], h1s = bnsh[col0 + 1];
            float s2 = bnsc[col0 + 2], h2s = bnsh[col0 + 2];
            float s3 = bnsc[col0 + 3], h3s = bnsh[col0 + 3];
#pragma unroll
            for (int ni = 0; ni < 4; ni++) {
                int w = ni * 16 + ln;
                f32x4 a = acc[mi][ni];
                float t0 = a.x * s0 + h0s, t1 = a.y * s1 + h1s;
                float t2 = a.z * s2 + h2s, t3 = a.w * s3 + h3s;
                ushort4 o;
                o.x = f2h(t0 / (1.f + __expf(-t0)));
                o.y = f2h(t1 / (1.f + __expf(-t1)));
                o.z = f2h(t2 / (1.f + __expf(-t2)));
                o.w = f2h(t3 / (1.f + __expf(-t3)));
                *(ushort4*)&outNHWC[(((size_t)b * 66 + orow + 1) * 64 + w) * Cout
                                    + coBase + col0] = o;
            }
        }
    } else {
        // conv2: y_hi NCHW fp16 + y_hiT NHWC fp16
#pragma unroll
        for (int mi = 0; mi < 4; mi++) {
            int col0 = mi * 16 + q * 4;
#pragma unroll
            for (int ni = 0; ni < 4; ni++) {
                int w = ni * 16 + ln;
                f32x4 a = acc[mi][ni];
                float vals[4] = {a.x, a.y, a.z, a.w};
                ushort4 hv;
                unsigned short* hvp = (unsigned short*)&hv;
#pragma unroll
                for (int r = 0; r < 4; r++) {
                    int co = coBase + col0 + r;
                    float t = vals[r] * bnsc[col0 + r] + bnsh[col0 + r];
                    float s = t / (1.f + __expf(-t));
                    hvp[r] = f2h(s);
                    yhi[(((size_t)b * Cout + co) * 64 + orow) * 64 + w] = hvp[r];
                }
                *(ushort4*)&yhiT[((size_t)b * 4096 + orow * 64 + w) * Cout
                                 + coBase + col0] = hv;
            }
        }
    }
}

// ---------------------------------------------------------------------------
// scores = (y . y^T)/16, fp16 MFMA, SYMMETRIC: only upper-triangle 64x64 tile
// pairs are computed (10 of 16); each writes its tile and the transpose.
// y_hi: [b][c=256][n=4096] fp16. Block: 4 waves of 32x32. K-chunks of 128,
// XOR-swizzled LDS (conflict-free ds_read_b128).
// grid: (10, 1, 16)
// ---------------------------------------------------------------------------
__global__ __launch_bounds__(256) void scores_mfma_kernel(
    const unsigned short* __restrict__ yhi, float* __restrict__ scores)
{
    static const int TI[10] = {0,0,0,0,1,1,1,2,2,3};
    static const int TJ[10] = {0,1,2,3,1,2,3,2,3,3};
    const int b  = blockIdx.z;
    const int ti = TI[blockIdx.x], tj = TJ[blockIdx.x];
    const int cB = ti * 64;
    const int dB = tj * 64;
    const int tid  = threadIdx.x;
    const int wid  = tid >> 6;
    const int lane = tid & 63;
    const int ln   = lane & 15;
    const int q    = lane >> 4;
    const int wm   = wid >> 1, wn = wid & 1;

    __shared__ unsigned short As[64 * 128];  // 16 KB, rows cB..cB+63, swizzled
    __shared__ unsigned short Bs[64 * 128];  // 16 KB, rows dB..dB+63, swizzled

    // staging geometry: issue j covers rows j*4..j*4+3 of a tile; lane ->
    // row rl = lane>>4, stored k-group g = lane&15, global group g^(r&7)
    const int rl = lane >> 4;
    const int gl = lane & 15;

    f32x4 acc[2][2] = {};

    for (int ck = 0; ck < 32; ck++) {
        const int n0 = ck * 128;
        for (int it = wid; it < 32; it += 4) {
            const int tile = it >> 4;
            const int j = it & 15;
            const int r = j * 4 + rl;
            const int gq = gl ^ (r & 7);
            const int rowAbs = (tile ? dB : cB) + r;
            const unsigned short* g =
                yhi + ((size_t)b * 256 + rowAbs) * 4096 + n0 + gq * 8;
            GLDS(g, (tile ? Bs : As) + j * 512);
        }
        __syncthreads();

#pragma unroll
        for (int kwin = 0; kwin < 4; kwin++) {
            half8 ah[2], bh[2];
#pragma unroll
            for (int mi = 0; mi < 2; mi++) {
                int row = wm * 32 + mi * 16 + ln;
                ah[mi] = *(const half8*)&As[row * 128 + ((kwin * 4 + q) ^ (ln & 7)) * 8];
            }
#pragma unroll
            for (int ni = 0; ni < 2; ni++) {
                int row = wn * 32 + ni * 16 + ln;
                bh[ni] = *(const half8*)&Bs[row * 128 + ((kwin * 4 + q) ^ (ln & 7)) * 8];
            }
#pragma unroll
            for (int mi = 0; mi < 2; mi++)
#pragma unroll
                for (int ni = 0; ni < 2; ni++)
                    acc[mi][ni] = __builtin_amdgcn_mfma_f32_16x16x32_f16(
                        ah[mi], bh[ni], acc[mi][ni], 0, 0, 0);
        }
        __syncthreads();
    }

#pragma unroll
    for (int mi = 0; mi < 2; mi++)
#pragma unroll
        for (int ni = 0; ni < 2; ni++) {
            f32x4 a = acc[mi][ni];
            float vals[4];
            vals[0] = a.x * INV_T; vals[1] = a.y * INV_T;
            vals[2] = a.z * INV_T; vals[3] = a.w * INV_T;
            int c0 = cB + wm * 32 + mi * 16 + q * 4;
            int d  = dB + wn * 32 + ni * 16 + ln;
#pragma unroll
            for (int r = 0; r < 4; r++)
                scores[((size_t)b * C1 + c0 + r) * C1 + d] = vals[r];
            if (ti != tj) {   // mirror tile
                float4 tv = {vals[0], vals[1], vals[2], vals[3]};
                *(float4*)&scores[((size_t)b * C1 + d) * C1 + c0] = tv;
            }
        }
}

// ---------------------------------------------------------------------------
// Row softmax over 256 entries; reads fp32 scores, writes fp16 attn.
// ---------------------------------------------------------------------------
__global__ __launch_bounds__(64) void softmax_kernel(
    const float* __restrict__ scores, unsigned short* __restrict__ attn16)
{
    const int row = blockIdx.x;
    const float* p = scores + (size_t)row * C1;
    const int lane = threadIdx.x;

    float4 v = ((const float4*)p)[lane];
    float m = fmaxf(fmaxf(v.x, v.y), fmaxf(v.z, v.w));
#pragma unroll
    for (int off = 32; off >= 1; off >>= 1)
        m = fmaxf(m, __shfl_xor(m, off, 64));

    float4 e;
    e.x = expf(v.x - m); e.y = expf(v.y - m);
    e.z = expf(v.z - m); e.w = expf(v.w - m);
    float s = e.x + e.y + e.z + e.w;
#pragma unroll
    for (int off = 32; off >= 1; off >>= 1)
        s += __shfl_xor(s, off, 64);
    float inv = 1.f / s;
    ushort4 o;
    o.x = f2h(e.x * inv); o.y = f2h(e.y * inv);
    o.z = f2h(e.z * inv); o.w = f2h(e.w * inv);
    *(ushort4*)&attn16[(size_t)row * C1 + lane * 4] = o;
}

// ---------------------------------------------------------------------------
// out[b][c][n] = x[b][c][n] + sum_d attn[c][d] * y[d][n]  via fp16 MFMA.
// A = attn16 [b][c][d], B = yhiT [b][n][d] (both k=d contiguous).
// Block tile 64c x 128n, 4 waves of 32x64. K-chunks of 64 (4 chunks).
// grid: (32, 4, 16)
// ---------------------------------------------------------------------------
__global__ __launch_bounds__(256) void out_mfma_kernel(
    const unsigned short* __restrict__ attn16, const unsigned short* __restrict__ yhiT,
    const float* __restrict__ x, float* __restrict__ out)
{
    const int b  = blockIdx.z;
    const int cB = blockIdx.y * 64;
    const int nB = blockIdx.x * 128;
    const int tid  = threadIdx.x;
    const int wid  = tid >> 6;
    const int lane = tid & 63;
    const int ln   = lane & 15;
    const int q    = lane >> 4;
    const int wm   = wid >> 1, wn = wid & 1;

    __shared__ unsigned short As[64 * 64];    //  8 KB
    __shared__ unsigned short Bs[128 * 64];   // 16 KB

    const int r8 = lane >> 3;
    const int gq = (lane & 7) ^ r8;

    f32x4 acc[2][4] = {};

    for (int ck = 0; ck < 4; ck++) {
        const int d0 = ck * 64;
        for (int it = wid; it < 24; it += 4) {
            if (it < 8) {
                const unsigned short* g =
                    attn16 + ((size_t)b * 256 + cB + it * 8 + r8) * 256 + d0 + gq * 8;
                GLDS(g, As + it * 512);
            } else {
                int j = it - 8;
                const unsigned short* g =
                    yhiT + ((size_t)b * 4096 + nB + j * 8 + r8) * 256 + d0 + gq * 8;
                GLDS(g, Bs + j * 512);
            }
        }
        __syncthreads();

#pragma unroll
        for (int kwin = 0; kwin < 2; kwin++) {
            const int cc = (((kwin * 4 + q) ^ (ln & 7))) * 8;
            half8 af[2], bfr[4];
#pragma unroll
            for (int mi = 0; mi < 2; mi++)
                af[mi] = *(const half8*)&As[(wm * 32 + mi * 16 + ln) * 64 + cc];
#pragma unroll
            for (int ni = 0; ni < 4; ni++)
                bfr[ni] = *(const half8*)&Bs[(wn * 64 + ni * 16 + ln) * 64 + cc];
#pragma unroll
            for (int mi = 0; mi < 2; mi++)
#pragma unroll
                for (int ni = 0; ni < 4; ni++)
                    acc[mi][ni] = __builtin_amdgcn_mfma_f32_16x16x32_f16(
                        af[mi], bfr[ni], acc[mi][ni], 0, 0, 0);
        }
        __syncthreads();
    }

#pragma unroll
    for (int mi = 0; mi < 2; mi++)
#pragma unroll
        for (int ni = 0; ni < 4; ni++) {
            f32x4 a = acc[mi][ni];
            float vals[4] = {a.x, a.y, a.z, a.w};
#pragma unroll
            for (int r = 0; r < 4; r++) {
                int c = cB + wm * 32 + mi * 16 + q * 4 + r;
                int n = nB + wn * 64 + ni * 16 + ln;
                size_t o = ((size_t)b * C1 + c) * NN + n;
                out[o] = x[o] + vals[r];
            }
        }
}

// ---------------------------------------------------------------------------
extern "C" void kernel_launch(void* const* d_in, const int* in_sizes, int n_in,
                              void* d_out, int out_size, void* d_ws, size_t ws_size,
                              hipStream_t stream)
{
    const float* x  = (const float*)d_in[0];
    const float* w1 = (const float*)d_in[1];
    const float* g1 = (const float*)d_in[2];
    const float* b1 = (const float*)d_in[3];
    const float* m1 = (const float*)d_in[4];
    const float* v1 = (const float*)d_in[5];
    const float* w2 = (const float*)d_in[6];
    const float* g2 = (const float*)d_in[7];
    const float* b2 = (const float*)d_in[8];
    const float* m2 = (const float*)d_in[9];
    const float* v2 = (const float*)d_in[10];
    float* out = (float*)d_out;

    // workspace (86.6 MB total):
    //  xh [17,301,504 us] -- dead after conv1, REUSED as y_hi [16,777,216 us]
    //  y1h [8,650,752 us] -- dead after conv2, REUSED as sc (fp32) + attn16
    unsigned short* xh   = (unsigned short*)d_ws;
    unsigned short* y1h  = xh  + (size_t)17301504;
    unsigned short* wt1  = y1h + (size_t)8650752;
    unsigned short* wt2  = wt1 + (size_t)294912;
    unsigned short* yhiT = wt2 + (size_t)294912;
    unsigned short* yhi  = xh;                         // alias (xh dead)
    float*          sc   = (float*)y1h;                // alias (y1h dead)
    unsigned short* attn16 = (unsigned short*)(sc + 1048576);

    // pre-pass
    nchw_to_nhwc_f16<<<dim3(C1 / 64, 66, BB), 256, 0, stream>>>(x, xh, C1);
    pack_w_kernel<<<(9 * CHD * C1 + 255) / 256, 256, 0, stream>>>(w1, wt1, CHD, C1);
    pack_w_kernel<<<(9 * C1 * CHD + 255) / 256, 256, 0, stream>>>(w2, wt2, C1, CHD);
    zero_y1h_pads<<<256, 256, 0, stream>>>(y1h);

    // conv1: 256 -> 128, fp16 NHWC out (padded rows)
    conv_mfma_kernel<<<dim3(CHD / 64, 16, BB), 256, 0, stream>>>(
        xh, wt1, g1, b1, m1, v1, y1h, nullptr, nullptr, C1, CHD);
    // conv2: 128 -> 256, y_hi NCHW + y_hiT NHWC (overwrites xh region with yhi)
    conv_mfma_kernel<<<dim3(C1 / 64, 16, BB), 256, 0, stream>>>(
        y1h, wt2, g2, b2, m2, v2, nullptr, yhi, yhiT, CHD, C1);

    // attention: symmetric fp16 MFMA scores -> softmax -> fp16 MFMA PV + residual
    scores_mfma_kernel<<<dim3(10, 1, BB), 256, 0, stream>>>(yhi, sc);
    softmax_kernel<<<dim3(BB * C1), 64, 0, stream>>>(sc, attn16);
    out_mfma_kernel<<<dim3(NN / 128, 4, BB), 256, 0, stream>>>(attn16, yhiT, x, out);
}